// Round 6
// baseline (541.601 us; speedup 1.0000x reference)
//
#include <hip/hip_runtime.h>

#define N_NODES 25000
#define N_EDGES 400000

static constexpr float INV_SQRT3 = 0.5773502691896257f;
static constexpr float PW0 = 0.20412414523193154f;   // sqrt(1/24)
static constexpr float PW1 = 0.35355339059327373f;   // sqrt(3/24)
static constexpr float SILU_NORM = 1.6791767923989418f;
static constexpr float SCC = 0.03125f;               // 1/sqrt(64) * 1/sqrt(16)
static constexpr float KP1C = PW1 * INV_SQRT3 * SCC;
static constexpr float Q4C  = PW0 * INV_SQRT3 * SCC;

typedef __attribute__((ext_vector_type(8))) short bf16x8;   // 8 bf16 = 4 VGPR
typedef __attribute__((ext_vector_type(4))) float f32x4;

__device__ __forceinline__ unsigned short f2bf(float x) {
    unsigned int u = __float_as_uint(x);
    u += 0x7FFFu + ((u >> 16) & 1u);        // RNE
    return (unsigned short)(u >> 16);
}

__device__ __forceinline__ bf16x8 pack8(const float* p) {
    float4 a = *(const float4*)p, b = *(const float4*)(p + 4);
    bf16x8 r;
    r[0] = (short)f2bf(a.x); r[1] = (short)f2bf(a.y);
    r[2] = (short)f2bf(a.z); r[3] = (short)f2bf(a.w);
    r[4] = (short)f2bf(b.x); r[5] = (short)f2bf(b.y);
    r[6] = (short)f2bf(b.z); r[7] = (short)f2bf(b.w);
    return r;
}

// ---------------- workspace layout (int units) ------------------------------
#define WS_CNT  0
#define WS_CUR  25000
#define WS_EIDX 50000
#define WS_W1T  450000              // 4096 ushort = 2048 ints
#define WS_W2T  452048              // 36864 ushort = 18432 ints
#define WS_REQ_BYTES ((size_t)(452048 + 18432) * 4)

// ============================================================================
// K1: fused prep (W1/W2 -> bf16 transposed, LINEAR [n][k] layout) + histogram.
// B-fragments are read straight from global in k_conv, so no swizzle needed.
// ============================================================================
__global__ __launch_bounds__(256) void k_preph(const int* __restrict__ edge_src,
                                               int* __restrict__ cnt,
                                               const float* __restrict__ W1,
                                               const float* __restrict__ W2,
                                               unsigned short* __restrict__ W1Tg,
                                               unsigned short* __restrict__ W2Tg)
{
    const int id = blockIdx.x * 256 + threadIdx.x;
    if (id < N_EDGES) atomicAdd(&cnt[edge_src[id]], 1);
    if (id < 64 * 64) {
        const int n = id >> 6, j = id & 63;
        W1Tg[n * 64 + j] = f2bf(W1[j * 64 + n]);
    }
    if (id < 576 * 64) {
        const int n = id / 64, k = id % 64;
        W2Tg[n * 64 + k] = f2bf(W2[k * 576 + n]);
    }
}

// ============================================================================
// K2: exclusive scan of cnt -> cur (single block, 1024 threads, 25 bins each)
// ============================================================================
__global__ __launch_bounds__(1024) void k_scan(const int* __restrict__ cnt,
                                               int* __restrict__ cur)
{
    __shared__ int sa[1024], sb[1024];
    const int t = threadIdx.x;
    const int base = t * 25;
    int loc[25];
    int s = 0;
#pragma unroll
    for (int q = 0; q < 25; ++q) {
        const int idx = base + q;
        const int v = (idx < N_NODES) ? cnt[idx] : 0;
        loc[q] = s; s += v;
    }
    sa[t] = s;
    __syncthreads();
    int* sp = sa; int* dp = sb;
    for (int d = 1; d < 1024; d <<= 1) {
        int v = sp[t];
        if (t >= d) v += sp[t - d];
        dp[t] = v;
        __syncthreads();
        int* tmp = sp; sp = dp; dp = tmp;
    }
    const int excl = sp[t] - s;
#pragma unroll
    for (int q = 0; q < 25; ++q) {
        const int idx = base + q;
        if (idx < N_NODES) cur[idx] = excl + loc[q];
    }
}

// ============================================================================
// K3: scatter edge ids into sorted-by-src positions
// ============================================================================
__global__ __launch_bounds__(256) void k_scatter(const int* __restrict__ edge_src,
                                                 int* __restrict__ cur,
                                                 int* __restrict__ eidx)
{
    const int e = blockIdx.x * 256 + threadIdx.x;
    if (e < N_EDGES) {
        const int pos = atomicAdd(&cur[edge_src[e]], 1);
        eidx[pos] = e;
    }
}

// ============================================================================
// K4: MFMA fused conv. 64 sorted edges/block, 256 threads = 4 waves.
// B-operands (W1T / W2T, L2-resident, 80 KB total) load DIRECT from global:
// a wave's 64 lanes read exactly one contiguous 2 KB column-block per n-tile
// (cl -> 128B column, kgrp -> 16B chunk) -> perfectly coalesced, no LDS
// staging, no staging barriers. LDS = 33.5 KB -> 4 blocks/CU (vs R5's 2).
// ============================================================================
__global__ __launch_bounds__(256) void k_conv(
    const float* __restrict__ node_input,
    const int* __restrict__ edge_src,
    const int* __restrict__ edge_dst,
    const float* __restrict__ edge_attr,
    const float* __restrict__ dist_embedding,
    const unsigned short* __restrict__ W1Tg,
    const unsigned short* __restrict__ W2Tg,
    const int* __restrict__ eidx_g,
    float* __restrict__ out)
{
    __shared__ __align__(16) unsigned short sH[64 * 64];   // 8192 B bf16 H (swizzled)
    __shared__ float xq_s[64 * 56];                        // coefs per edge (14336 B)
    __shared__ float racc[64 * 40];                        // run accumulators (10240 B)
    __shared__ int   eidx_s[64], src_s[64], p0_s[64];

    const int t  = threadIdx.x;
    const int pb = blockIdx.x * 64;
    const int w = t >> 6, lane = t & 63;
    const int kgrp = lane >> 4;          // 0..3
    const int cl = lane & 15;

    // ---------------- phase B: edge meta + coefs -> LDS -------------------
    if (t < 64) {
        const int eid = eidx_g[pb + t];
        eidx_s[t] = eid;
        src_s[t]  = edge_src[eid];
        const int dst = edge_dst[eid];
        const float4* xr = (const float4*)(node_input + (size_t)dst * 40);
        float* xd = xq_s + t * 56;
        float xx[40];
#pragma unroll
        for (int i = 0; i < 10; ++i) {
            float4 v = xr[i];
            xx[i*4+0] = v.x; xx[i*4+1] = v.y; xx[i*4+2] = v.z; xx[i*4+3] = v.w;
            *(float4*)(xd + i * 4) = v;
        }
        const float4 yv = *(const float4*)(edge_attr + (size_t)eid * 4);
        xd[48] = PW0 * SCC * yv.x;   // q0
        xd[49] = KP1C * yv.x;        // q3
        xd[50] = yv.y; xd[51] = yv.z; xd[52] = yv.w;
#pragma unroll
        for (int u = 0; u < 8; ++u)  // cB[u] = y1 . x1[u]
            xd[40 + u] = yv.y * xx[16 + u*3] + yv.z * xx[16 + u*3 + 1] + yv.w * xx[16 + u*3 + 2];
    }
    for (int i = t; i < 64 * 40; i += 256) racc[i] = 0.f;
    __syncthreads();

    // ---------------- phase C: GEMM1 (MFMA, B from global) + silu -> H ----
    {
        const int er = w * 16 + cl;
        const float* dp = dist_embedding + (size_t)eidx_s[er] * 64 + kgrp * 8;
        bf16x8 a0 = pack8(dp);          // k = kgrp*8 + j
        bf16x8 a1 = pack8(dp + 32);     // k = 32 + kgrp*8 + j
#pragma unroll
        for (int nt = 0; nt < 4; ++nt) {
            const unsigned short* bp = W1Tg + (nt * 16 + cl) * 64 + kgrp * 8;
            bf16x8 b0 = *(const bf16x8*)bp;
            bf16x8 b1 = *(const bf16x8*)(bp + 32);
            f32x4 c = {0.f, 0.f, 0.f, 0.f};
            c = __builtin_amdgcn_mfma_f32_16x16x32_bf16(a0, b0, c, 0, 0, 0);
            c = __builtin_amdgcn_mfma_f32_16x16x32_bf16(a1, b1, c, 0, 0, 0);
#pragma unroll
            for (int r = 0; r < 4; ++r) {
                const float zz = 0.125f * c[r];
                const float h = SILU_NORM * __fdividef(zz, 1.f + __expf(-zz));
                const int hr = w * 16 + kgrp * 4 + r;      // edge row
                const int hc = nt * 16 + cl;               // k-dim col
                sH[hr * 64 + (hc ^ ((hr & 7) << 3))] = f2bf(h);
            }
        }
    }
    if (t < 64) {
        int p = t;
        while (p > 0 && src_s[p - 1] == src_s[t]) --p;
        p0_s[t] = p;
    }
    __syncthreads();

    // ---------------- phase D: GEMM2 (MFMA, B from global) + TP epilogue --
    const int arow = w * 16 + cl;
    const unsigned short* ap = sH + arow * 64;
    const int ax = (cl & 7) << 3;
    bf16x8 A0 = *(const bf16x8*)(ap + ((kgrp * 8) ^ ax));
    bf16x8 A1 = *(const bf16x8*)(ap + ((32 + kgrp * 8) ^ ax));

    float r1a[4] = {0,0,0,0}, r4a[4] = {0,0,0,0}, Tt[4] = {0,0,0,0};
    float P0[4] = {0,0,0,0}, P1[4] = {0,0,0,0}, P2[4] = {0,0,0,0};
    const int e0 = w * 16 + kgrp * 4;    // lane's first edge row (C rows)
    const unsigned short* bbase = W2Tg + cl * 64 + kgrp * 8;

#pragma unroll
    for (int gnt = 0; gnt < 36; ++gnt) {
        const unsigned short* bp = bbase + gnt * 1024;   // col = gnt*16+cl
        bf16x8 B0 = *(const bf16x8*)bp;
        bf16x8 B1 = *(const bf16x8*)(bp + 32);
        f32x4 c = {0.f, 0.f, 0.f, 0.f};
        c = __builtin_amdgcn_mfma_f32_16x16x32_bf16(A0, B0, c, 0, 0, 0);
        c = __builtin_amdgcn_mfma_f32_16x16x32_bf16(A1, B1, c, 0, 0, 0);
        if (gnt < 16) {                       // region 1: u = gnt, wo = cl
#pragma unroll
            for (int r = 0; r < 4; ++r) r1a[r] += xq_s[(e0 + r) * 56 + gnt] * c[r];
        } else if (gnt < 24) {                // region 2: u = 2(gnt-16)+(lane>>3&1)
            const int u = (gnt - 16) * 2 + ((lane >> 3) & 1);
#pragma unroll
            for (int r = 0; r < 4; ++r) Tt[r] += xq_s[(e0 + r) * 56 + u] * c[r];
        } else if (gnt < 28) {                // region 3: u = 2(gnt-24)+(lane>>3&1)
            const int u = (gnt - 24) * 2 + ((lane >> 3) & 1);
#pragma unroll
            for (int r = 0; r < 4; ++r) {
                const float* xp = xq_s + (e0 + r) * 56 + 16 + u * 3;
                P0[r] += xp[0] * c[r];
                P1[r] += xp[1] * c[r];
                P2[r] += xp[2] * c[r];
            }
        } else {                              // region 4: u = gnt-28, wo = cl
            const int u = gnt - 28;
#pragma unroll
            for (int r = 0; r < 4; ++r) r4a[r] += xq_s[(e0 + r) * 56 + 40 + u] * c[r];
        }
    }

    // ---------------- final assembly + block-local reduction --------------
#pragma unroll
    for (int r = 0; r < 4; ++r) {
        const int e = e0 + r;
        const float v = xq_s[e * 56 + 48] * r1a[r] + Q4C * r4a[r];
        atomicAdd(&racc[p0_s[e] * 40 + cl], v);
    }
#pragma unroll
    for (int r = 0; r < 4; ++r) {
        Tt[r] += __shfl_xor(Tt[r], 8);
        P0[r] += __shfl_xor(P0[r], 8);
        P1[r] += __shfl_xor(P1[r], 8);
        P2[r] += __shfl_xor(P2[r], 8);
    }
    if ((lane & 8) == 0) {
        const int wo = lane & 7;
#pragma unroll
        for (int r = 0; r < 4; ++r) {
            const int e = e0 + r;
            const float q3  = xq_s[e * 56 + 49];
            const float y1x = xq_s[e * 56 + 50];
            const float y1y = xq_s[e * 56 + 51];
            const float y1z = xq_s[e * 56 + 52];
            float* rp = &racc[p0_s[e] * 40 + 16 + wo * 3];
            atomicAdd(rp + 0, KP1C * y1x * Tt[r] + q3 * P0[r]);
            atomicAdd(rp + 1, KP1C * y1y * Tt[r] + q3 * P1[r]);
            atomicAdd(rp + 2, KP1C * y1z * Tt[r] + q3 * P2[r]);
        }
    }
    __syncthreads();
    if (t < 64 && p0_s[t] == t) {
        float* op = out + (size_t)src_s[t] * 40;
        const float* rp = racc + t * 40;
#pragma unroll
        for (int cc = 0; cc < 40; ++cc) atomicAdd(op + cc, rp[cc]);
    }
}

// ============================================================================
// Fallback (ws too small): R0's proven per-edge atomic kernel
// ============================================================================
template <int NC>
__device__ __forceinline__ void gemm_cols(const float* __restrict__ base,
                                          const float (&h)[64], float (&w)[NC]) {
#pragma unroll
    for (int i = 0; i < NC; ++i) w[i] = 0.f;
#pragma unroll
    for (int k = 0; k < 64; ++k) {
        const float4* r4 = (const float4*)(base + k * 576);
        const float hk = h[k];
#pragma unroll
        for (int q = 0; q < NC / 4; ++q) {
            float4 a = r4[q];
            w[q * 4 + 0] += hk * a.x;  w[q * 4 + 1] += hk * a.y;
            w[q * 4 + 2] += hk * a.z;  w[q * 4 + 3] += hk * a.w;
        }
    }
}

__global__ __launch_bounds__(256) void conv_atomic(
    const float* __restrict__ node_input,
    const int* __restrict__ edge_src,
    const int* __restrict__ edge_dst,
    const float* __restrict__ edge_attr,
    const float* __restrict__ dist_embedding,
    const float* __restrict__ W1,
    const float* __restrict__ W2,
    float* __restrict__ out)
{
    __shared__ float sX[256 * 44];
    const int e = blockIdx.x * 256 + threadIdx.x;
    if (e >= N_EDGES) return;
    float* xs = &sX[threadIdx.x * 44];

    float z[64];
#pragma unroll
    for (int k = 0; k < 64; ++k) z[k] = 0.f;
    const float4* dp = (const float4*)(dist_embedding + (size_t)e * 64);
#pragma unroll 2
    for (int j4 = 0; j4 < 16; ++j4) {
        float4 d4 = dp[j4];
        float dj[4] = {d4.x, d4.y, d4.z, d4.w};
#pragma unroll
        for (int r = 0; r < 4; ++r) {
            const float4* w1r = (const float4*)(W1 + (j4 * 4 + r) * 64);
            const float dv = dj[r];
#pragma unroll
            for (int k4 = 0; k4 < 16; ++k4) {
                float4 a = w1r[k4];
                z[k4 * 4 + 0] += dv * a.x; z[k4 * 4 + 1] += dv * a.y;
                z[k4 * 4 + 2] += dv * a.z; z[k4 * 4 + 3] += dv * a.w;
            }
        }
    }
    float h[64];
#pragma unroll
    for (int k = 0; k < 64; ++k) {
        const float zz = 0.125f * z[k];
        h[k] = SILU_NORM * __fdividef(zz, 1.f + __expf(-zz));
    }
    const int dst = edge_dst[e];
    const float4* xr = (const float4*)(node_input + (size_t)dst * 40);
    float4* xd = (float4*)xs;
#pragma unroll
    for (int i = 0; i < 10; ++i) xd[i] = xr[i];
    const float4 yv = *(const float4*)(edge_attr + (size_t)e * 4);
    const float q0 = PW0 * yv.x * SCC;
    const float q4 = PW0 * INV_SQRT3 * SCC;
    const float q20 = KP1C * yv.y, q21 = KP1C * yv.z, q22 = KP1C * yv.w;
    const float q3 = KP1C * yv.x;
    float o0[16], o1[24];
#pragma unroll
    for (int i = 0; i < 16; ++i) o0[i] = 0.f;
#pragma unroll
    for (int i = 0; i < 24; ++i) o1[i] = 0.f;
#pragma unroll 1
    for (int u = 0; u < 16; ++u) {
        float w[16];
        gemm_cols<16>(W2 + u * 16, h, w);
        const float coef = q0 * xs[u];
#pragma unroll
        for (int i = 0; i < 16; ++i) o0[i] += coef * w[i];
    }
#pragma unroll 1
    for (int u = 0; u < 16; ++u) {
        float w[8];
        gemm_cols<8>(W2 + 256 + u * 8, h, w);
        const float xv = xs[u];
        const float c0 = q20 * xv, c1 = q21 * xv, c2 = q22 * xv;
#pragma unroll
        for (int i = 0; i < 8; ++i) {
            o1[i * 3 + 0] += c0 * w[i]; o1[i * 3 + 1] += c1 * w[i]; o1[i * 3 + 2] += c2 * w[i];
        }
    }
#pragma unroll 1
    for (int u = 0; u < 8; ++u) {
        float w[8];
        gemm_cols<8>(W2 + 384 + u * 8, h, w);
        const float c0 = q3 * xs[16 + u * 3 + 0];
        const float c1 = q3 * xs[16 + u * 3 + 1];
        const float c2 = q3 * xs[16 + u * 3 + 2];
#pragma unroll
        for (int i = 0; i < 8; ++i) {
            o1[i * 3 + 0] += c0 * w[i]; o1[i * 3 + 1] += c1 * w[i]; o1[i * 3 + 2] += c2 * w[i];
        }
    }
#pragma unroll 1
    for (int u = 0; u < 8; ++u) {
        float w[16];
        gemm_cols<16>(W2 + 448 + u * 16, h, w);
        const float b = q4 * (xs[16 + u * 3 + 0] * yv.y +
                              xs[16 + u * 3 + 1] * yv.z +
                              xs[16 + u * 3 + 2] * yv.w);
#pragma unroll
        for (int i = 0; i < 16; ++i) o0[i] += b * w[i];
    }
    const int src = edge_src[e];
    float* op = out + (size_t)src * 40;
#pragma unroll
    for (int i = 0; i < 16; ++i) atomicAdd(op + i, o0[i]);
#pragma unroll
    for (int i = 0; i < 24; ++i) atomicAdd(op + 16 + i, o1[i]);
}

// ============================================================================
extern "C" void kernel_launch(void* const* d_in, const int* in_sizes, int n_in,
                              void* d_out, int out_size, void* d_ws, size_t ws_size,
                              hipStream_t stream)
{
    const float* node_input     = (const float*)d_in[0];
    const int*   edge_src       = (const int*)d_in[1];
    const int*   edge_dst       = (const int*)d_in[2];
    const float* edge_attr      = (const float*)d_in[3];
    const float* dist_embedding = (const float*)d_in[4];
    const float* W1             = (const float*)d_in[5];
    const float* W2             = (const float*)d_in[6];
    float* out = (float*)d_out;

    hipMemsetAsync(out, 0, (size_t)out_size * sizeof(float), stream);

    if (ws_size < WS_REQ_BYTES || d_ws == nullptr) {
        dim3 grid((N_EDGES + 255) / 256);
        conv_atomic<<<grid, 256, 0, stream>>>(node_input, edge_src, edge_dst,
                                              edge_attr, dist_embedding, W1, W2, out);
        return;
    }

    int* wsI = (int*)d_ws;
    int* cnt  = wsI + WS_CNT;
    int* cur  = wsI + WS_CUR;
    int* eidx = wsI + WS_EIDX;
    unsigned short* W1Tg = (unsigned short*)(wsI + WS_W1T);
    unsigned short* W2Tg = (unsigned short*)(wsI + WS_W2T);

    hipMemsetAsync(cnt, 0, (size_t)N_NODES * sizeof(int), stream);
    k_preph<<<dim3((N_EDGES + 255) / 256), 256, 0, stream>>>(edge_src, cnt,
                                                             W1, W2, W1Tg, W2Tg);
    k_scan<<<dim3(1), 1024, 0, stream>>>(cnt, cur);
    k_scatter<<<dim3((N_EDGES + 255) / 256), 256, 0, stream>>>(edge_src, cur, eidx);
    k_conv<<<dim3(N_EDGES / 64), 256, 0, stream>>>(node_input, edge_src, edge_dst,
                                                   edge_attr, dist_embedding,
                                                   W1Tg, W2Tg, eidx, out);
}

// Round 7
// 525.686 us; speedup vs baseline: 1.0303x; 1.0303x over previous
//
#include <hip/hip_runtime.h>

#define N_NODES 25000
#define N_EDGES 400000

static constexpr float INV_SQRT3 = 0.5773502691896257f;
static constexpr float PW0 = 0.20412414523193154f;   // sqrt(1/24)
static constexpr float PW1 = 0.35355339059327373f;   // sqrt(3/24)
static constexpr float SILU_NORM = 1.6791767923989418f;
static constexpr float SCC = 0.03125f;               // 1/sqrt(64) * 1/sqrt(16)
static constexpr float KP1C = PW1 * INV_SQRT3 * SCC;
static constexpr float Q4C  = PW0 * INV_SQRT3 * SCC;

typedef __attribute__((ext_vector_type(8))) short bf16x8;   // 8 bf16 = 4 VGPR
typedef __attribute__((ext_vector_type(4))) float f32x4;

__device__ __forceinline__ unsigned short f2bf(float x) {
    unsigned int u = __float_as_uint(x);
    u += 0x7FFFu + ((u >> 16) & 1u);        // RNE
    return (unsigned short)(u >> 16);
}

__device__ __forceinline__ bf16x8 pack8(const float* p) {
    float4 a = *(const float4*)p, b = *(const float4*)(p + 4);
    bf16x8 r;
    r[0] = (short)f2bf(a.x); r[1] = (short)f2bf(a.y);
    r[2] = (short)f2bf(a.z); r[3] = (short)f2bf(a.w);
    r[4] = (short)f2bf(b.x); r[5] = (short)f2bf(b.y);
    r[6] = (short)f2bf(b.z); r[7] = (short)f2bf(b.w);
    return r;
}

// ---------------- workspace layout (int units) ------------------------------
#define WS_CNT  0
#define WS_CUR  25000
#define WS_EIDX 50000
#define WS_W1T  450000              // 4096 ushort = 2048 ints
#define WS_W2T  452048              // 36864 ushort = 18432 ints
#define WS_REQ_BYTES ((size_t)(452048 + 18432) * 4)

// ============================================================================
// K1: fused prep (W1/W2 -> bf16 transposed, XOR-swizzled [n][k^((n&7)<<3)])
//     + histogram of edge_src.
// ============================================================================
__global__ __launch_bounds__(256) void k_preph(const int* __restrict__ edge_src,
                                               int* __restrict__ cnt,
                                               const float* __restrict__ W1,
                                               const float* __restrict__ W2,
                                               unsigned short* __restrict__ W1Tg,
                                               unsigned short* __restrict__ W2Tg)
{
    const int id = blockIdx.x * 256 + threadIdx.x;
    if (id < N_EDGES) atomicAdd(&cnt[edge_src[id]], 1);
    if (id < 64 * 64) {
        const int n = id >> 6, j = id & 63;
        W1Tg[n * 64 + (j ^ ((n & 7) << 3))] = f2bf(W1[j * 64 + n]);
    }
    if (id < 576 * 64) {
        const int n = id / 64, k = id % 64;
        W2Tg[n * 64 + (k ^ ((n & 7) << 3))] = f2bf(W2[k * 576 + n]);
    }
}

// ============================================================================
// K2: exclusive scan of cnt -> cur
// ============================================================================
__global__ __launch_bounds__(1024) void k_scan(const int* __restrict__ cnt,
                                               int* __restrict__ cur)
{
    __shared__ int sa[1024], sb[1024];
    const int t = threadIdx.x;
    const int base = t * 25;
    int loc[25];
    int s = 0;
#pragma unroll
    for (int q = 0; q < 25; ++q) {
        const int idx = base + q;
        const int v = (idx < N_NODES) ? cnt[idx] : 0;
        loc[q] = s; s += v;
    }
    sa[t] = s;
    __syncthreads();
    int* sp = sa; int* dp = sb;
    for (int d = 1; d < 1024; d <<= 1) {
        int v = sp[t];
        if (t >= d) v += sp[t - d];
        dp[t] = v;
        __syncthreads();
        int* tmp = sp; sp = dp; dp = tmp;
    }
    const int excl = sp[t] - s;
#pragma unroll
    for (int q = 0; q < 25; ++q) {
        const int idx = base + q;
        if (idx < N_NODES) cur[idx] = excl + loc[q];
    }
}

// ============================================================================
// K3: scatter edge ids into sorted-by-src positions
// ============================================================================
__global__ __launch_bounds__(256) void k_scatter(const int* __restrict__ edge_src,
                                                 int* __restrict__ cur,
                                                 int* __restrict__ eidx)
{
    const int e = blockIdx.x * 256 + threadIdx.x;
    if (e < N_EDGES) {
        const int pos = atomicAdd(&cur[edge_src[e]], 1);
        eidx[pos] = e;
    }
}

// ============================================================================
// K4: persistent MFMA conv. 512 blocks; block half = bid&1 owns n-cols
// [half*288, half*288+288); stages W1T + its W2T half ONCE, then loops
// ~24 edge-tiles of 64 sorted edges with no weight staging. Half-blocks'
// TP contributions are linear -> partial atomicAdds combine correctly.
// ============================================================================
template<int HALF>
__device__ __forceinline__ void conv_tile_D(
    const unsigned short* __restrict__ sB,
    const unsigned short* __restrict__ sH,
    const float* __restrict__ xq_s,
    float* __restrict__ racc,
    const int* __restrict__ p0_s,
    int w, int lane, int kgrp, int cl)
{
    const int bx = (cl & 7) << 3;
    const int arow = w * 16 + cl;
    const unsigned short* ap = sH + arow * 64;
    bf16x8 A0 = *(const bf16x8*)(ap + ((kgrp * 8) ^ bx));
    bf16x8 A1 = *(const bf16x8*)(ap + ((32 + kgrp * 8) ^ bx));

    float r1a[4] = {0,0,0,0}, r4a[4] = {0,0,0,0}, Tt[4] = {0,0,0,0};
    float P0[4] = {0,0,0,0}, P1[4] = {0,0,0,0}, P2[4] = {0,0,0,0};
    const int e0 = w * 16 + kgrp * 4;
    const unsigned short* b2 = sB + 4096;       // W2T half panel

#pragma unroll
    for (int nt = 0; nt < 18; ++nt) {
        const unsigned short* bp = b2 + (nt * 16 + cl) * 64;
        bf16x8 B0 = *(const bf16x8*)(bp + ((kgrp * 8) ^ bx));
        bf16x8 B1 = *(const bf16x8*)(bp + ((32 + kgrp * 8) ^ bx));
        f32x4 c = {0.f, 0.f, 0.f, 0.f};
        c = __builtin_amdgcn_mfma_f32_16x16x32_bf16(A0, B0, c, 0, 0, 0);
        c = __builtin_amdgcn_mfma_f32_16x16x32_bf16(A1, B1, c, 0, 0, 0);
        const int gnt = HALF * 18 + nt;         // compile-time
        if (gnt < 16) {                         // region 1: u = gnt, wo = cl
#pragma unroll
            for (int r = 0; r < 4; ++r) r1a[r] += xq_s[(e0 + r) * 56 + gnt] * c[r];
        } else if (gnt < 24) {                  // region 2
            const int u = (gnt - 16) * 2 + ((lane >> 3) & 1);
#pragma unroll
            for (int r = 0; r < 4; ++r) Tt[r] += xq_s[(e0 + r) * 56 + u] * c[r];
        } else if (gnt < 28) {                  // region 3
            const int u = (gnt - 24) * 2 + ((lane >> 3) & 1);
#pragma unroll
            for (int r = 0; r < 4; ++r) {
                const float* xp = xq_s + (e0 + r) * 56 + 16 + u * 3;
                P0[r] += xp[0] * c[r];
                P1[r] += xp[1] * c[r];
                P2[r] += xp[2] * c[r];
            }
        } else {                                // region 4: u = gnt-28, wo = cl
            const int u = gnt - 28;
#pragma unroll
            for (int r = 0; r < 4; ++r) r4a[r] += xq_s[(e0 + r) * 56 + 40 + u] * c[r];
        }
    }

    // ---- assembly into run accumulators (partial per half; linear) -------
#pragma unroll
    for (int r = 0; r < 4; ++r) {
        const int e = e0 + r;
        const float v = xq_s[e * 56 + 48] * r1a[r] + Q4C * r4a[r];
        atomicAdd(&racc[p0_s[e] * 40 + cl], v);
    }
#pragma unroll
    for (int r = 0; r < 4; ++r) {
        Tt[r] += __shfl_xor(Tt[r], 8);
        P0[r] += __shfl_xor(P0[r], 8);
        P1[r] += __shfl_xor(P1[r], 8);
        P2[r] += __shfl_xor(P2[r], 8);
    }
    if ((lane & 8) == 0) {
        const int wo = lane & 7;
#pragma unroll
        for (int r = 0; r < 4; ++r) {
            const int e = e0 + r;
            const float q3  = xq_s[e * 56 + 49];
            const float y1x = xq_s[e * 56 + 50];
            const float y1y = xq_s[e * 56 + 51];
            const float y1z = xq_s[e * 56 + 52];
            float* rp = &racc[p0_s[e] * 40 + 16 + wo * 3];
            atomicAdd(rp + 0, KP1C * y1x * Tt[r] + q3 * P0[r]);
            atomicAdd(rp + 1, KP1C * y1y * Tt[r] + q3 * P1[r]);
            atomicAdd(rp + 2, KP1C * y1z * Tt[r] + q3 * P2[r]);
        }
    }
}

__global__ __launch_bounds__(256) void k_conv(
    const float* __restrict__ node_input,
    const int* __restrict__ edge_src,
    const int* __restrict__ edge_dst,
    const float* __restrict__ edge_attr,
    const float* __restrict__ dist_embedding,
    const unsigned short* __restrict__ W1Tg,
    const unsigned short* __restrict__ W2Tg,
    const int* __restrict__ eidx_g,
    float* __restrict__ out)
{
    __shared__ __align__(16) unsigned short sB[352 * 64];  // W1T(8KB) + W2T half(36.9KB)
    __shared__ __align__(16) unsigned short sH[64 * 64];   // 8 KB
    __shared__ float xq_s[64 * 56];                        // 14.3 KB
    __shared__ float racc[64 * 40];                        // 10.2 KB
    __shared__ int   eidx_s[64], src_s[64], p0_s[64];

    const int t    = threadIdx.x;
    const int half = blockIdx.x & 1;
    const int bgrp = blockIdx.x >> 1;                      // 0..255
    const int w = t >> 6, lane = t & 63;
    const int kgrp = lane >> 4, cl = lane & 15;
    const int bx = (cl & 7) << 3;

    // ---- stage W1T + our W2T half ONCE: 2816 uint4 = 11/thread ----------
    {
        const uint4* s1 = (const uint4*)W1Tg;
        uint4* d1 = (uint4*)sB;
        d1[t] = s1[t];
        d1[t + 256] = s1[t + 256];
        const uint4* s2 = (const uint4*)(W2Tg + (size_t)half * 18432);
        uint4* d2 = (uint4*)(sB + 4096);
#pragma unroll
        for (int i = 0; i < 9; ++i) d2[t + i * 256] = s2[t + i * 256];
    }

    for (int tile = bgrp; tile < N_EDGES / 64; tile += 256) {
        const int pb = tile * 64;
        __syncthreads();                 // sB ready / prev flush complete
        for (int i = t; i < 64 * 40; i += 256) racc[i] = 0.f;

        // ---------------- phase B: edge meta + coefs -> LDS ---------------
        if (t < 64) {
            const int eid = eidx_g[pb + t];
            eidx_s[t] = eid;
            src_s[t]  = edge_src[eid];
            const int dst = edge_dst[eid];
            const float4* xr = (const float4*)(node_input + (size_t)dst * 40);
            float* xd = xq_s + t * 56;
            float xx[40];
#pragma unroll
            for (int i = 0; i < 10; ++i) {
                float4 v = xr[i];
                xx[i*4+0] = v.x; xx[i*4+1] = v.y; xx[i*4+2] = v.z; xx[i*4+3] = v.w;
                *(float4*)(xd + i * 4) = v;
            }
            const float4 yv = *(const float4*)(edge_attr + (size_t)eid * 4);
            xd[48] = PW0 * SCC * yv.x;   // q0
            xd[49] = KP1C * yv.x;        // q3
            xd[50] = yv.y; xd[51] = yv.z; xd[52] = yv.w;
#pragma unroll
            for (int u = 0; u < 8; ++u)  // cB[u] = y1 . x1[u]
                xd[40 + u] = yv.y * xx[16 + u*3] + yv.z * xx[16 + u*3 + 1] + yv.w * xx[16 + u*3 + 2];
        }
        __syncthreads();

        // ---------------- phase C: GEMM1 (MFMA) + silu -> sH --------------
        {
            const int er = w * 16 + cl;
            const float* dp = dist_embedding + (size_t)eidx_s[er] * 64 + kgrp * 8;
            bf16x8 a0 = pack8(dp);
            bf16x8 a1 = pack8(dp + 32);
#pragma unroll
            for (int nt = 0; nt < 4; ++nt) {
                const unsigned short* bp = sB + (nt * 16 + cl) * 64;
                bf16x8 b0 = *(const bf16x8*)(bp + ((kgrp * 8) ^ bx));
                bf16x8 b1 = *(const bf16x8*)(bp + ((32 + kgrp * 8) ^ bx));
                f32x4 c = {0.f, 0.f, 0.f, 0.f};
                c = __builtin_amdgcn_mfma_f32_16x16x32_bf16(a0, b0, c, 0, 0, 0);
                c = __builtin_amdgcn_mfma_f32_16x16x32_bf16(a1, b1, c, 0, 0, 0);
#pragma unroll
                for (int r = 0; r < 4; ++r) {
                    const float zz = 0.125f * c[r];
                    const float h = SILU_NORM * __fdividef(zz, 1.f + __expf(-zz));
                    const int hr = w * 16 + kgrp * 4 + r;
                    const int hc = nt * 16 + cl;
                    sH[hr * 64 + (hc ^ ((hr & 7) << 3))] = f2bf(h);
                }
            }
        }
        if (t < 64) {
            int p = t;
            while (p > 0 && src_s[p - 1] == src_s[t]) --p;
            p0_s[t] = p;
        }
        __syncthreads();

        // ---------------- phase D + epilogue (compile-time half) ----------
        if (half == 0)
            conv_tile_D<0>(sB, sH, xq_s, racc, p0_s, w, lane, kgrp, cl);
        else
            conv_tile_D<1>(sB, sH, xq_s, racc, p0_s, w, lane, kgrp, cl);
        __syncthreads();

        // ---------------- flush run heads to global -----------------------
        if (t < 64 && p0_s[t] == t) {
            float* op = out + (size_t)src_s[t] * 40;
            const float* rp = racc + t * 40;
#pragma unroll
            for (int cc = 0; cc < 40; ++cc) atomicAdd(op + cc, rp[cc]);
        }
    }
}

// ============================================================================
// Fallback (ws too small): R0's proven per-edge atomic kernel
// ============================================================================
template <int NC>
__device__ __forceinline__ void gemm_cols(const float* __restrict__ base,
                                          const float (&h)[64], float (&w)[NC]) {
#pragma unroll
    for (int i = 0; i < NC; ++i) w[i] = 0.f;
#pragma unroll
    for (int k = 0; k < 64; ++k) {
        const float4* r4 = (const float4*)(base + k * 576);
        const float hk = h[k];
#pragma unroll
        for (int q = 0; q < NC / 4; ++q) {
            float4 a = r4[q];
            w[q * 4 + 0] += hk * a.x;  w[q * 4 + 1] += hk * a.y;
            w[q * 4 + 2] += hk * a.z;  w[q * 4 + 3] += hk * a.w;
        }
    }
}

__global__ __launch_bounds__(256) void conv_atomic(
    const float* __restrict__ node_input,
    const int* __restrict__ edge_src,
    const int* __restrict__ edge_dst,
    const float* __restrict__ edge_attr,
    const float* __restrict__ dist_embedding,
    const float* __restrict__ W1,
    const float* __restrict__ W2,
    float* __restrict__ out)
{
    __shared__ float sX[256 * 44];
    const int e = blockIdx.x * 256 + threadIdx.x;
    if (e >= N_EDGES) return;
    float* xs = &sX[threadIdx.x * 44];

    float z[64];
#pragma unroll
    for (int k = 0; k < 64; ++k) z[k] = 0.f;
    const float4* dp = (const float4*)(dist_embedding + (size_t)e * 64);
#pragma unroll 2
    for (int j4 = 0; j4 < 16; ++j4) {
        float4 d4 = dp[j4];
        float dj[4] = {d4.x, d4.y, d4.z, d4.w};
#pragma unroll
        for (int r = 0; r < 4; ++r) {
            const float4* w1r = (const float4*)(W1 + (j4 * 4 + r) * 64);
            const float dv = dj[r];
#pragma unroll
            for (int k4 = 0; k4 < 16; ++k4) {
                float4 a = w1r[k4];
                z[k4 * 4 + 0] += dv * a.x; z[k4 * 4 + 1] += dv * a.y;
                z[k4 * 4 + 2] += dv * a.z; z[k4 * 4 + 3] += dv * a.w;
            }
        }
    }
    float h[64];
#pragma unroll
    for (int k = 0; k < 64; ++k) {
        const float zz = 0.125f * z[k];
        h[k] = SILU_NORM * __fdividef(zz, 1.f + __expf(-zz));
    }
    const int dst = edge_dst[e];
    const float4* xr = (const float4*)(node_input + (size_t)dst * 40);
    float4* xd = (float4*)xs;
#pragma unroll
    for (int i = 0; i < 10; ++i) xd[i] = xr[i];
    const float4 yv = *(const float4*)(edge_attr + (size_t)e * 4);
    const float q0 = PW0 * yv.x * SCC;
    const float q4 = PW0 * INV_SQRT3 * SCC;
    const float q20 = KP1C * yv.y, q21 = KP1C * yv.z, q22 = KP1C * yv.w;
    const float q3 = KP1C * yv.x;
    float o0[16], o1[24];
#pragma unroll
    for (int i = 0; i < 16; ++i) o0[i] = 0.f;
#pragma unroll
    for (int i = 0; i < 24; ++i) o1[i] = 0.f;
#pragma unroll 1
    for (int u = 0; u < 16; ++u) {
        float w[16];
        gemm_cols<16>(W2 + u * 16, h, w);
        const float coef = q0 * xs[u];
#pragma unroll
        for (int i = 0; i < 16; ++i) o0[i] += coef * w[i];
    }
#pragma unroll 1
    for (int u = 0; u < 16; ++u) {
        float w[8];
        gemm_cols<8>(W2 + 256 + u * 8, h, w);
        const float xv = xs[u];
        const float c0 = q20 * xv, c1 = q21 * xv, c2 = q22 * xv;
#pragma unroll
        for (int i = 0; i < 8; ++i) {
            o1[i * 3 + 0] += c0 * w[i]; o1[i * 3 + 1] += c1 * w[i]; o1[i * 3 + 2] += c2 * w[i];
        }
    }
#pragma unroll 1
    for (int u = 0; u < 8; ++u) {
        float w[8];
        gemm_cols<8>(W2 + 384 + u * 8, h, w);
        const float c0 = q3 * xs[16 + u * 3 + 0];
        const float c1 = q3 * xs[16 + u * 3 + 1];
        const float c2 = q3 * xs[16 + u * 3 + 2];
#pragma unroll
        for (int i = 0; i < 8; ++i) {
            o1[i * 3 + 0] += c0 * w[i]; o1[i * 3 + 1] += c1 * w[i]; o1[i * 3 + 2] += c2 * w[i];
        }
    }
#pragma unroll 1
    for (int u = 0; u < 8; ++u) {
        float w[16];
        gemm_cols<16>(W2 + 448 + u * 16, h, w);
        const float b = q4 * (xs[16 + u * 3 + 0] * yv.y +
                              xs[16 + u * 3 + 1] * yv.z +
                              xs[16 + u * 3 + 2] * yv.w);
#pragma unroll
        for (int i = 0; i < 16; ++i) o0[i] += b * w[i];
    }
    const int src = edge_src[e];
    float* op = out + (size_t)src * 40;
#pragma unroll
    for (int i = 0; i < 16; ++i) atomicAdd(op + i, o0[i]);
#pragma unroll
    for (int i = 0; i < 24; ++i) atomicAdd(op + 16 + i, o1[i]);
}

// ============================================================================
extern "C" void kernel_launch(void* const* d_in, const int* in_sizes, int n_in,
                              void* d_out, int out_size, void* d_ws, size_t ws_size,
                              hipStream_t stream)
{
    const float* node_input     = (const float*)d_in[0];
    const int*   edge_src       = (const int*)d_in[1];
    const int*   edge_dst       = (const int*)d_in[2];
    const float* edge_attr      = (const float*)d_in[3];
    const float* dist_embedding = (const float*)d_in[4];
    const float* W1             = (const float*)d_in[5];
    const float* W2             = (const float*)d_in[6];
    float* out = (float*)d_out;

    hipMemsetAsync(out, 0, (size_t)out_size * sizeof(float), stream);

    if (ws_size < WS_REQ_BYTES || d_ws == nullptr) {
        dim3 grid((N_EDGES + 255) / 256);
        conv_atomic<<<grid, 256, 0, stream>>>(node_input, edge_src, edge_dst,
                                              edge_attr, dist_embedding, W1, W2, out);
        return;
    }

    int* wsI = (int*)d_ws;
    int* cnt  = wsI + WS_CNT;
    int* cur  = wsI + WS_CUR;
    int* eidx = wsI + WS_EIDX;
    unsigned short* W1Tg = (unsigned short*)(wsI + WS_W1T);
    unsigned short* W2Tg = (unsigned short*)(wsI + WS_W2T);

    hipMemsetAsync(cnt, 0, (size_t)N_NODES * sizeof(int), stream);
    k_preph<<<dim3((N_EDGES + 255) / 256), 256, 0, stream>>>(edge_src, cnt,
                                                             W1, W2, W1Tg, W2Tg);
    k_scan<<<dim3(1), 1024, 0, stream>>>(cnt, cur);
    k_scatter<<<dim3((N_EDGES + 255) / 256), 256, 0, stream>>>(edge_src, cur, eidx);
    k_conv<<<dim3(512), 256, 0, stream>>>(node_input, edge_src, edge_dst,
                                          edge_attr, dist_embedding,
                                          W1Tg, W2Tg, eidx, out);
}

// Round 8
// 465.807 us; speedup vs baseline: 1.1627x; 1.1285x over previous
//
#include <hip/hip_runtime.h>

#define N_NODES 25000
#define N_EDGES 400000

static constexpr float INV_SQRT3 = 0.5773502691896257f;
static constexpr float PW0 = 0.20412414523193154f;   // sqrt(1/24)
static constexpr float PW1 = 0.35355339059327373f;   // sqrt(3/24)
static constexpr float SILU_NORM = 1.6791767923989418f;
static constexpr float SCC = 0.03125f;               // 1/sqrt(64) * 1/sqrt(16)
static constexpr float KP1C = PW1 * INV_SQRT3 * SCC;
static constexpr float Q4C  = PW0 * INV_SQRT3 * SCC;

typedef __attribute__((ext_vector_type(8))) short bf16x8;   // 8 bf16 = 4 VGPR
typedef __attribute__((ext_vector_type(4))) float f32x4;

#define XQS 60            // xq row stride (floats): 16B-aligned, kgrp offsets
                          // (4*60 words) % 32 = 16 -> 2-way bank alias (free)

__device__ __forceinline__ unsigned short f2bf(float x) {
    unsigned int u = __float_as_uint(x);
    u += 0x7FFFu + ((u >> 16) & 1u);        // RNE
    return (unsigned short)(u >> 16);
}

__device__ __forceinline__ bf16x8 pack8(const float* p) {
    float4 a = *(const float4*)p, b = *(const float4*)(p + 4);
    bf16x8 r;
    r[0] = (short)f2bf(a.x); r[1] = (short)f2bf(a.y);
    r[2] = (short)f2bf(a.z); r[3] = (short)f2bf(a.w);
    r[4] = (short)f2bf(b.x); r[5] = (short)f2bf(b.y);
    r[6] = (short)f2bf(b.z); r[7] = (short)f2bf(b.w);
    return r;
}

// ---------------- workspace layout (int units) ------------------------------
#define WS_CNT  0
#define WS_CUR  25000
#define WS_EIDX 50000
#define WS_W1T  450000              // 4096 ushort = 2048 ints
#define WS_W2T  452048              // 36864 ushort = 18432 ints
#define WS_REQ_BYTES ((size_t)(452048 + 18432) * 4)

// ============================================================================
// K1: fused prep (W1/W2 -> bf16 transposed, LINEAR [n][k]) + histogram.
// (B-fragments are consumed straight from global; R6 verified this layout.)
// ============================================================================
__global__ __launch_bounds__(256) void k_preph(const int* __restrict__ edge_src,
                                               int* __restrict__ cnt,
                                               const float* __restrict__ W1,
                                               const float* __restrict__ W2,
                                               unsigned short* __restrict__ W1Tg,
                                               unsigned short* __restrict__ W2Tg)
{
    const int id = blockIdx.x * 256 + threadIdx.x;
    if (id < N_EDGES) atomicAdd(&cnt[edge_src[id]], 1);
    if (id < 64 * 64) {
        const int n = id >> 6, j = id & 63;
        W1Tg[n * 64 + j] = f2bf(W1[j * 64 + n]);
    }
    if (id < 576 * 64) {
        const int n = id / 64, k = id % 64;
        W2Tg[n * 64 + k] = f2bf(W2[k * 576 + n]);
    }
}

// ============================================================================
// K2: exclusive scan of cnt -> cur
// ============================================================================
__global__ __launch_bounds__(1024) void k_scan(const int* __restrict__ cnt,
                                               int* __restrict__ cur)
{
    __shared__ int sa[1024], sb[1024];
    const int t = threadIdx.x;
    const int base = t * 25;
    int loc[25];
    int s = 0;
#pragma unroll
    for (int q = 0; q < 25; ++q) {
        const int idx = base + q;
        const int v = (idx < N_NODES) ? cnt[idx] : 0;
        loc[q] = s; s += v;
    }
    sa[t] = s;
    __syncthreads();
    int* sp = sa; int* dp = sb;
    for (int d = 1; d < 1024; d <<= 1) {
        int v = sp[t];
        if (t >= d) v += sp[t - d];
        dp[t] = v;
        __syncthreads();
        int* tmp = sp; sp = dp; dp = tmp;
    }
    const int excl = sp[t] - s;
#pragma unroll
    for (int q = 0; q < 25; ++q) {
        const int idx = base + q;
        if (idx < N_NODES) cur[idx] = excl + loc[q];
    }
}

// ============================================================================
// K3: scatter edge ids into sorted-by-src positions
// ============================================================================
__global__ __launch_bounds__(256) void k_scatter(const int* __restrict__ edge_src,
                                                 int* __restrict__ cur,
                                                 int* __restrict__ eidx)
{
    const int e = blockIdx.x * 256 + threadIdx.x;
    if (e < N_EDGES) {
        const int pos = atomicAdd(&cur[edge_src[e]], 1);
        eidx[pos] = e;
    }
}

// ============================================================================
// K4: MFMA fused conv. 64 sorted edges/block, 256 threads = 4 waves.
// No weight LDS staging at all: B-fragments stream from L2 via a manual
// ring-4 software pipeline (~6 loads in flight -> L2 latency hidden).
// LDS = 34.6 KB -> 4 blocks/CU; xq stride 60 kills the 4-way coef-read
// bank conflict of the 56-stride layout.
// ============================================================================
__global__ __launch_bounds__(256, 4) void k_conv(
    const float* __restrict__ node_input,
    const int* __restrict__ edge_src,
    const int* __restrict__ edge_dst,
    const float* __restrict__ edge_attr,
    const float* __restrict__ dist_embedding,
    const unsigned short* __restrict__ W1Tg,
    const unsigned short* __restrict__ W2Tg,
    const int* __restrict__ eidx_g,
    float* __restrict__ out)
{
    __shared__ __align__(16) unsigned short sH[64 * 64];   // 8 KB bf16 H (swizzled)
    __shared__ float xq_s[64 * XQS];                       // 15.4 KB coefs
    __shared__ float racc[64 * 40];                        // 10.2 KB run accumulators
    __shared__ int   eidx_s[64], src_s[64], p0_s[64];

    const int t  = threadIdx.x;
    const int pb = blockIdx.x * 64;
    const int w = t >> 6, lane = t & 63;
    const int kgrp = lane >> 4;          // 0..3
    const int cl = lane & 15;

    // ---------------- phase B: edge meta + coefs -> LDS -------------------
    if (t < 64) {
        const int eid = eidx_g[pb + t];
        eidx_s[t] = eid;
        src_s[t]  = edge_src[eid];
        const int dst = edge_dst[eid];
        const float4* xr = (const float4*)(node_input + (size_t)dst * 40);
        float* xd = xq_s + t * XQS;
        float xx[40];
#pragma unroll
        for (int i = 0; i < 10; ++i) {
            float4 v = xr[i];
            xx[i*4+0] = v.x; xx[i*4+1] = v.y; xx[i*4+2] = v.z; xx[i*4+3] = v.w;
            *(float4*)(xd + i * 4) = v;
        }
        const float4 yv = *(const float4*)(edge_attr + (size_t)eid * 4);
        xd[48] = PW0 * SCC * yv.x;   // q0
        xd[49] = KP1C * yv.x;        // q3
        xd[50] = yv.y; xd[51] = yv.z; xd[52] = yv.w;
#pragma unroll
        for (int u = 0; u < 8; ++u)  // cB[u] = y1 . x1[u]
            xd[40 + u] = yv.y * xx[16 + u*3] + yv.z * xx[16 + u*3 + 1] + yv.w * xx[16 + u*3 + 2];
    }
    for (int i = t; i < 64 * 40; i += 256) racc[i] = 0.f;
    __syncthreads();

    // ---------------- phase C: GEMM1 (MFMA, B direct global) + silu -> H --
    {
        const int er = w * 16 + cl;
        const float* dp = dist_embedding + (size_t)eidx_s[er] * 64 + kgrp * 8;
        bf16x8 a0 = pack8(dp);
        bf16x8 a1 = pack8(dp + 32);
        // issue all 8 B-loads up front (one latency for the whole phase)
        bf16x8 wb0[4], wb1[4];
#pragma unroll
        for (int nt = 0; nt < 4; ++nt) {
            const unsigned short* bp = W1Tg + (nt * 16 + cl) * 64 + kgrp * 8;
            wb0[nt] = *(const bf16x8*)bp;
            wb1[nt] = *(const bf16x8*)(bp + 32);
        }
#pragma unroll
        for (int nt = 0; nt < 4; ++nt) {
            f32x4 c = {0.f, 0.f, 0.f, 0.f};
            c = __builtin_amdgcn_mfma_f32_16x16x32_bf16(a0, wb0[nt], c, 0, 0, 0);
            c = __builtin_amdgcn_mfma_f32_16x16x32_bf16(a1, wb1[nt], c, 0, 0, 0);
#pragma unroll
            for (int r = 0; r < 4; ++r) {
                const float zz = 0.125f * c[r];
                const float h = SILU_NORM * __fdividef(zz, 1.f + __expf(-zz));
                const int hr = w * 16 + kgrp * 4 + r;      // edge row
                const int hc = nt * 16 + cl;               // k-dim col
                sH[hr * 64 + (hc ^ ((hr & 7) << 3))] = f2bf(h);
            }
        }
    }
    if (t < 64) {
        int p = t;
        while (p > 0 && src_s[p - 1] == src_s[t]) --p;
        p0_s[t] = p;
    }
    __syncthreads();

    // ---------------- phase D: GEMM2 (ring-4 global prefetch) + epilogue --
    const int arow = w * 16 + cl;
    const unsigned short* ap = sH + arow * 64;
    const int ax = (cl & 7) << 3;
    bf16x8 A0 = *(const bf16x8*)(ap + ((kgrp * 8) ^ ax));
    bf16x8 A1 = *(const bf16x8*)(ap + ((32 + kgrp * 8) ^ ax));

    float r1a[4] = {0,0,0,0}, r4a[4] = {0,0,0,0}, Tt[4] = {0,0,0,0};
    float P0[4] = {0,0,0,0}, P1[4] = {0,0,0,0}, P2[4] = {0,0,0,0};
    const int e0 = w * 16 + kgrp * 4;    // lane's first edge row (C rows)
    const unsigned short* bbase = W2Tg + cl * 64 + kgrp * 8;

    bf16x8 Rb0[4], Rb1[4];               // prefetch ring (static idx when unrolled)
#pragma unroll
    for (int i = 0; i < 3; ++i) {
        const unsigned short* bp = bbase + i * 1024;
        Rb0[i] = *(const bf16x8*)bp;
        Rb1[i] = *(const bf16x8*)(bp + 32);
    }
#pragma unroll
    for (int gnt = 0; gnt < 36; ++gnt) {
        if (gnt < 33) {                  // prefetch gnt+3
            const unsigned short* bp = bbase + (gnt + 3) * 1024;
            Rb0[(gnt + 3) & 3] = *(const bf16x8*)bp;
            Rb1[(gnt + 3) & 3] = *(const bf16x8*)(bp + 32);
        }
        f32x4 c = {0.f, 0.f, 0.f, 0.f};
        c = __builtin_amdgcn_mfma_f32_16x16x32_bf16(A0, Rb0[gnt & 3], c, 0, 0, 0);
        c = __builtin_amdgcn_mfma_f32_16x16x32_bf16(A1, Rb1[gnt & 3], c, 0, 0, 0);
        if (gnt < 16) {                       // region 1: u = gnt, wo = cl
#pragma unroll
            for (int r = 0; r < 4; ++r) r1a[r] += xq_s[(e0 + r) * XQS + gnt] * c[r];
        } else if (gnt < 24) {                // region 2: u = 2(gnt-16)+(lane>>3&1)
            const int u = (gnt - 16) * 2 + ((lane >> 3) & 1);
#pragma unroll
            for (int r = 0; r < 4; ++r) Tt[r] += xq_s[(e0 + r) * XQS + u] * c[r];
        } else if (gnt < 28) {                // region 3: u = 2(gnt-24)+(lane>>3&1)
            const int u = (gnt - 24) * 2 + ((lane >> 3) & 1);
#pragma unroll
            for (int r = 0; r < 4; ++r) {
                const float* xp = xq_s + (e0 + r) * XQS + 16 + u * 3;
                P0[r] += xp[0] * c[r];
                P1[r] += xp[1] * c[r];
                P2[r] += xp[2] * c[r];
            }
        } else {                              // region 4: u = gnt-28, wo = cl
            const int u = gnt - 28;
#pragma unroll
            for (int r = 0; r < 4; ++r) r1a[r] = r1a[r], r4a[r] += xq_s[(e0 + r) * XQS + 40 + u] * c[r];
        }
    }

    // ---------------- final assembly + block-local reduction --------------
#pragma unroll
    for (int r = 0; r < 4; ++r) {
        const int e = e0 + r;
        const float v = xq_s[e * XQS + 48] * r1a[r] + Q4C * r4a[r];
        atomicAdd(&racc[p0_s[e] * 40 + cl], v);
    }
#pragma unroll
    for (int r = 0; r < 4; ++r) {
        Tt[r] += __shfl_xor(Tt[r], 8);
        P0[r] += __shfl_xor(P0[r], 8);
        P1[r] += __shfl_xor(P1[r], 8);
        P2[r] += __shfl_xor(P2[r], 8);
    }
    if ((lane & 8) == 0) {
        const int wo = lane & 7;
#pragma unroll
        for (int r = 0; r < 4; ++r) {
            const int e = e0 + r;
            const float q3  = xq_s[e * XQS + 49];
            const float y1x = xq_s[e * XQS + 50];
            const float y1y = xq_s[e * XQS + 51];
            const float y1z = xq_s[e * XQS + 52];
            float* rp = &racc[p0_s[e] * 40 + 16 + wo * 3];
            atomicAdd(rp + 0, KP1C * y1x * Tt[r] + q3 * P0[r]);
            atomicAdd(rp + 1, KP1C * y1y * Tt[r] + q3 * P1[r]);
            atomicAdd(rp + 2, KP1C * y1z * Tt[r] + q3 * P2[r]);
        }
    }
    __syncthreads();
    if (t < 64 && p0_s[t] == t) {
        float* op = out + (size_t)src_s[t] * 40;
        const float* rp = racc + t * 40;
#pragma unroll
        for (int cc = 0; cc < 40; ++cc) atomicAdd(op + cc, rp[cc]);
    }
}

// ============================================================================
// Fallback (ws too small): R0's proven per-edge atomic kernel
// ============================================================================
template <int NC>
__device__ __forceinline__ void gemm_cols(const float* __restrict__ base,
                                          const float (&h)[64], float (&w)[NC]) {
#pragma unroll
    for (int i = 0; i < NC; ++i) w[i] = 0.f;
#pragma unroll
    for (int k = 0; k < 64; ++k) {
        const float4* r4 = (const float4*)(base + k * 576);
        const float hk = h[k];
#pragma unroll
        for (int q = 0; q < NC / 4; ++q) {
            float4 a = r4[q];
            w[q * 4 + 0] += hk * a.x;  w[q * 4 + 1] += hk * a.y;
            w[q * 4 + 2] += hk * a.z;  w[q * 4 + 3] += hk * a.w;
        }
    }
}

__global__ __launch_bounds__(256) void conv_atomic(
    const float* __restrict__ node_input,
    const int* __restrict__ edge_src,
    const int* __restrict__ edge_dst,
    const float* __restrict__ edge_attr,
    const float* __restrict__ dist_embedding,
    const float* __restrict__ W1,
    const float* __restrict__ W2,
    float* __restrict__ out)
{
    __shared__ float sX[256 * 44];
    const int e = blockIdx.x * 256 + threadIdx.x;
    if (e >= N_EDGES) return;
    float* xs = &sX[threadIdx.x * 44];

    float z[64];
#pragma unroll
    for (int k = 0; k < 64; ++k) z[k] = 0.f;
    const float4* dp = (const float4*)(dist_embedding + (size_t)e * 64);
#pragma unroll 2
    for (int j4 = 0; j4 < 16; ++j4) {
        float4 d4 = dp[j4];
        float dj[4] = {d4.x, d4.y, d4.z, d4.w};
#pragma unroll
        for (int r = 0; r < 4; ++r) {
            const float4* w1r = (const float4*)(W1 + (j4 * 4 + r) * 64);
            const float dv = dj[r];
#pragma unroll
            for (int k4 = 0; k4 < 16; ++k4) {
                float4 a = w1r[k4];
                z[k4 * 4 + 0] += dv * a.x; z[k4 * 4 + 1] += dv * a.y;
                z[k4 * 4 + 2] += dv * a.z; z[k4 * 4 + 3] += dv * a.w;
            }
        }
    }
    float h[64];
#pragma unroll
    for (int k = 0; k < 64; ++k) {
        const float zz = 0.125f * z[k];
        h[k] = SILU_NORM * __fdividef(zz, 1.f + __expf(-zz));
    }
    const int dst = edge_dst[e];
    const float4* xr = (const float4*)(node_input + (size_t)dst * 40);
    float4* xd = (float4*)xs;
#pragma unroll
    for (int i = 0; i < 10; ++i) xd[i] = xr[i];
    const float4 yv = *(const float4*)(edge_attr + (size_t)e * 4);
    const float q0 = PW0 * yv.x * SCC;
    const float q4 = PW0 * INV_SQRT3 * SCC;
    const float q20 = KP1C * yv.y, q21 = KP1C * yv.z, q22 = KP1C * yv.w;
    const float q3 = KP1C * yv.x;
    float o0[16], o1[24];
#pragma unroll
    for (int i = 0; i < 16; ++i) o0[i] = 0.f;
#pragma unroll
    for (int i = 0; i < 24; ++i) o1[i] = 0.f;
#pragma unroll 1
    for (int u = 0; u < 16; ++u) {
        float w[16];
        gemm_cols<16>(W2 + u * 16, h, w);
        const float coef = q0 * xs[u];
#pragma unroll
        for (int i = 0; i < 16; ++i) o0[i] += coef * w[i];
    }
#pragma unroll 1
    for (int u = 0; u < 16; ++u) {
        float w[8];
        gemm_cols<8>(W2 + 256 + u * 8, h, w);
        const float xv = xs[u];
        const float c0 = q20 * xv, c1 = q21 * xv, c2 = q22 * xv;
#pragma unroll
        for (int i = 0; i < 8; ++i) {
            o1[i * 3 + 0] += c0 * w[i]; o1[i * 3 + 1] += c1 * w[i]; o1[i * 3 + 2] += c2 * w[i];
        }
    }
#pragma unroll 1
    for (int u = 0; u < 8; ++u) {
        float w[8];
        gemm_cols<8>(W2 + 384 + u * 8, h, w);
        const float c0 = q3 * xs[16 + u * 3 + 0];
        const float c1 = q3 * xs[16 + u * 3 + 1];
        const float c2 = q3 * xs[16 + u * 3 + 2];
#pragma unroll
        for (int i = 0; i < 8; ++i) {
            o1[i * 3 + 0] += c0 * w[i]; o1[i * 3 + 1] += c1 * w[i]; o1[i * 3 + 2] += c2 * w[i];
        }
    }
#pragma unroll 1
    for (int u = 0; u < 8; ++u) {
        float w[16];
        gemm_cols<16>(W2 + 448 + u * 16, h, w);
        const float b = q4 * (xs[16 + u * 3 + 0] * yv.y +
                              xs[16 + u * 3 + 1] * yv.z +
                              xs[16 + u * 3 + 2] * yv.w);
#pragma unroll
        for (int i = 0; i < 16; ++i) o0[i] += b * w[i];
    }
    const int src = edge_src[e];
    float* op = out + (size_t)src * 40;
#pragma unroll
    for (int i = 0; i < 16; ++i) atomicAdd(op + i, o0[i]);
#pragma unroll
    for (int i = 0; i < 24; ++i) atomicAdd(op + 16 + i, o1[i]);
}

// ============================================================================
extern "C" void kernel_launch(void* const* d_in, const int* in_sizes, int n_in,
                              void* d_out, int out_size, void* d_ws, size_t ws_size,
                              hipStream_t stream)
{
    const float* node_input     = (const float*)d_in[0];
    const int*   edge_src       = (const int*)d_in[1];
    const int*   edge_dst       = (const int*)d_in[2];
    const float* edge_attr      = (const float*)d_in[3];
    const float* dist_embedding = (const float*)d_in[4];
    const float* W1             = (const float*)d_in[5];
    const float* W2             = (const float*)d_in[6];
    float* out = (float*)d_out;

    hipMemsetAsync(out, 0, (size_t)out_size * sizeof(float), stream);

    if (ws_size < WS_REQ_BYTES || d_ws == nullptr) {
        dim3 grid((N_EDGES + 255) / 256);
        conv_atomic<<<grid, 256, 0, stream>>>(node_input, edge_src, edge_dst,
                                              edge_attr, dist_embedding, W1, W2, out);
        return;
    }

    int* wsI = (int*)d_ws;
    int* cnt  = wsI + WS_CNT;
    int* cur  = wsI + WS_CUR;
    int* eidx = wsI + WS_EIDX;
    unsigned short* W1Tg = (unsigned short*)(wsI + WS_W1T);
    unsigned short* W2Tg = (unsigned short*)(wsI + WS_W2T);

    hipMemsetAsync(cnt, 0, (size_t)N_NODES * sizeof(int), stream);
    k_preph<<<dim3((N_EDGES + 255) / 256), 256, 0, stream>>>(edge_src, cnt,
                                                             W1, W2, W1Tg, W2Tg);
    k_scan<<<dim3(1), 1024, 0, stream>>>(cnt, cur);
    k_scatter<<<dim3((N_EDGES + 255) / 256), 256, 0, stream>>>(edge_src, cur, eidx);
    k_conv<<<dim3(N_EDGES / 64), 256, 0, stream>>>(node_input, edge_src, edge_dst,
                                                   edge_attr, dist_embedding,
                                                   W1Tg, W2Tg, eidx, out);
}

// Round 9
// 388.037 us; speedup vs baseline: 1.3957x; 1.2004x over previous
//
#include <hip/hip_runtime.h>

#define N_NODES 25000
#define N_EDGES 400000

static constexpr float INV_SQRT3 = 0.5773502691896257f;
static constexpr float PW0 = 0.20412414523193154f;   // sqrt(1/24)
static constexpr float PW1 = 0.35355339059327373f;   // sqrt(3/24)
static constexpr float SILU_NORM = 1.6791767923989418f;
static constexpr float SCC = 0.03125f;               // 1/sqrt(64) * 1/sqrt(16)
static constexpr float KP1C = PW1 * INV_SQRT3 * SCC;
static constexpr float Q4C  = PW0 * INV_SQRT3 * SCC;

typedef __attribute__((ext_vector_type(8))) short bf16x8;   // 8 bf16 = 4 VGPR
typedef __attribute__((ext_vector_type(4))) float f32x4;

#define XQS 60            // xq row stride: kgrp coef-read offsets -> 2-way (free)

__device__ __forceinline__ unsigned short f2bf(float x) {
    unsigned int u = __float_as_uint(x);
    u += 0x7FFFu + ((u >> 16) & 1u);        // RNE
    return (unsigned short)(u >> 16);
}

__device__ __forceinline__ bf16x8 pack2(float4 a, float4 b) {
    bf16x8 r;
    r[0] = (short)f2bf(a.x); r[1] = (short)f2bf(a.y);
    r[2] = (short)f2bf(a.z); r[3] = (short)f2bf(a.w);
    r[4] = (short)f2bf(b.x); r[5] = (short)f2bf(b.y);
    r[6] = (short)f2bf(b.z); r[7] = (short)f2bf(b.w);
    return r;
}

// ---------------- workspace layout (int units) ------------------------------
#define WS_CNT  0
#define WS_CUR  25000
#define WS_EIDX 50000
#define WS_W1T  450000              // 4096 ushort = 2048 ints
#define WS_W2T  452048              // 36864 ushort = 18432 ints
#define WS_REQ_BYTES ((size_t)(452048 + 18432) * 4)

// ============================================================================
// K1: prep + histogram. W1T LINEAR [n][j] (direct-global reads in phase C);
// W2T XOR-SWIZZLED [n][k^((n&7)<<3)] (LDS-staged + swizzled ds_read, R5-proven).
// ============================================================================
__global__ __launch_bounds__(256) void k_preph(const int* __restrict__ edge_src,
                                               int* __restrict__ cnt,
                                               const float* __restrict__ W1,
                                               const float* __restrict__ W2,
                                               unsigned short* __restrict__ W1Tg,
                                               unsigned short* __restrict__ W2Tg)
{
    const int id = blockIdx.x * 256 + threadIdx.x;
    if (id < N_EDGES) atomicAdd(&cnt[edge_src[id]], 1);
    if (id < 64 * 64) {
        const int n = id >> 6, j = id & 63;
        W1Tg[n * 64 + j] = f2bf(W1[j * 64 + n]);
    }
    if (id < 576 * 64) {
        const int n = id / 64, k = id % 64;
        W2Tg[n * 64 + (k ^ ((n & 7) << 3))] = f2bf(W2[k * 576 + n]);
    }
}

// ============================================================================
// K2: exclusive scan of cnt -> cur
// ============================================================================
__global__ __launch_bounds__(1024) void k_scan(const int* __restrict__ cnt,
                                               int* __restrict__ cur)
{
    __shared__ int sa[1024], sb[1024];
    const int t = threadIdx.x;
    const int base = t * 25;
    int loc[25];
    int s = 0;
#pragma unroll
    for (int q = 0; q < 25; ++q) {
        const int idx = base + q;
        const int v = (idx < N_NODES) ? cnt[idx] : 0;
        loc[q] = s; s += v;
    }
    sa[t] = s;
    __syncthreads();
    int* sp = sa; int* dp = sb;
    for (int d = 1; d < 1024; d <<= 1) {
        int v = sp[t];
        if (t >= d) v += sp[t - d];
        dp[t] = v;
        __syncthreads();
        int* tmp = sp; sp = dp; dp = tmp;
    }
    const int excl = sp[t] - s;
#pragma unroll
    for (int q = 0; q < 25; ++q) {
        const int idx = base + q;
        if (idx < N_NODES) cur[idx] = excl + loc[q];
    }
}

// ============================================================================
// K3: scatter edge ids into sorted-by-src positions
// ============================================================================
__global__ __launch_bounds__(256) void k_scatter(const int* __restrict__ edge_src,
                                                 int* __restrict__ cur,
                                                 int* __restrict__ eidx)
{
    const int e = blockIdx.x * 256 + threadIdx.x;
    if (e < N_EDGES) {
        const int pos = atomicAdd(&cur[edge_src[e]], 1);
        eidx[pos] = e;
    }
}

// ============================================================================
// K4: MFMA fused conv. 64 sorted edges/block, 256 threads = 4 waves.
// W2 staged to LDS in 6 phases of 96 cols (12.3 KB buffer, 3 uint4/thread);
// phase p+1's global loads are ISSUED during phase p's MFMA compute and
// ds_written after the barrier (T14) -> staging latency off the critical path.
// dist rows prefetched into regs at entry. LDS 46.6 KB -> 3 blocks/CU.
// ============================================================================
__global__ __launch_bounds__(256) void k_conv(
    const float* __restrict__ node_input,
    const int* __restrict__ edge_src,
    const int* __restrict__ edge_dst,
    const float* __restrict__ edge_attr,
    const float* __restrict__ dist_embedding,
    const unsigned short* __restrict__ W1Tg,
    const unsigned short* __restrict__ W2Tg,
    const int* __restrict__ eidx_g,
    float* __restrict__ out)
{
    __shared__ __align__(16) unsigned short sB[96 * 64];   // 12288 B (one sixth-panel)
    __shared__ __align__(16) unsigned short sH[64 * 64];   // 8192 B bf16 H (swizzled)
    __shared__ float xq_s[64 * XQS];                       // 15360 B coefs
    __shared__ float racc[64 * 40];                        // 10240 B run accumulators
    __shared__ int   src_s[64], p0_s[64];

    const int t  = threadIdx.x;
    const int pb = blockIdx.x * 64;
    const int w = t >> 6, lane = t & 63;
    const int kgrp = lane >> 4;          // 0..3
    const int cl = lane & 15;
    const int bx = (cl & 7) << 3;

    // ---- issue LONG-latency loads first: dist row + sB phase-0 ----------
    const int er = w * 16 + cl;
    const int eidA = eidx_g[pb + er];
    const float* dpp = dist_embedding + (size_t)eidA * 64 + kgrp * 8;
    float4 d0a = *(const float4*)dpp;
    float4 d0b = *(const float4*)(dpp + 4);
    float4 d1a = *(const float4*)(dpp + 32);
    float4 d1b = *(const float4*)(dpp + 36);

    const uint4* W2v = (const uint4*)W2Tg;
    uint4* sBv = (uint4*)sB;
    uint4 st0 = W2v[t];                  // phase 0: cols [0,96)
    uint4 st1 = W2v[t + 256];
    uint4 st2 = W2v[t + 512];

    // ---------------- phase B: edge meta + coefs -> LDS -------------------
    if (t < 64) {
        const int eid = eidx_g[pb + t];
        src_s[t] = edge_src[eid];
        const int dst = edge_dst[eid];
        const float4* xr = (const float4*)(node_input + (size_t)dst * 40);
        float* xd = xq_s + t * XQS;
        float xx[40];
#pragma unroll
        for (int i = 0; i < 10; ++i) {
            float4 v = xr[i];
            xx[i*4+0] = v.x; xx[i*4+1] = v.y; xx[i*4+2] = v.z; xx[i*4+3] = v.w;
            *(float4*)(xd + i * 4) = v;
        }
        const float4 yv = *(const float4*)(edge_attr + (size_t)eid * 4);
        xd[48] = PW0 * SCC * yv.x;   // q0
        xd[49] = KP1C * yv.x;        // q3
        xd[50] = yv.y; xd[51] = yv.z; xd[52] = yv.w;
#pragma unroll
        for (int u = 0; u < 8; ++u)  // cB[u] = y1 . x1[u]
            xd[40 + u] = yv.y * xx[16 + u*3] + yv.z * xx[16 + u*3 + 1] + yv.w * xx[16 + u*3 + 2];
    }
    for (int i = t; i < 64 * 40; i += 256) racc[i] = 0.f;
    __syncthreads();                     // xq/src ready

    // ---------------- phase C: GEMM1 (A prefetched, B direct) + silu ------
    {
        bf16x8 a0 = pack2(d0a, d0b);
        bf16x8 a1 = pack2(d1a, d1b);
        bf16x8 wb0[4], wb1[4];
#pragma unroll
        for (int nt = 0; nt < 4; ++nt) {
            const unsigned short* bp = W1Tg + (nt * 16 + cl) * 64 + kgrp * 8;
            wb0[nt] = *(const bf16x8*)bp;
            wb1[nt] = *(const bf16x8*)(bp + 32);
        }
#pragma unroll
        for (int nt = 0; nt < 4; ++nt) {
            f32x4 c = {0.f, 0.f, 0.f, 0.f};
            c = __builtin_amdgcn_mfma_f32_16x16x32_bf16(a0, wb0[nt], c, 0, 0, 0);
            c = __builtin_amdgcn_mfma_f32_16x16x32_bf16(a1, wb1[nt], c, 0, 0, 0);
#pragma unroll
            for (int r = 0; r < 4; ++r) {
                const float zz = 0.125f * c[r];
                const float h = SILU_NORM * __fdividef(zz, 1.f + __expf(-zz));
                const int hr = w * 16 + kgrp * 4 + r;
                const int hc = nt * 16 + cl;
                sH[hr * 64 + (hc ^ ((hr & 7) << 3))] = f2bf(h);
            }
        }
    }
    if (t < 64) {
        int p = t;
        while (p > 0 && src_s[p - 1] == src_s[t]) --p;
        p0_s[t] = p;
    }
    // write phase-0 panel (sB untouched so far; loads issued at entry)
    sBv[t] = st0; sBv[t + 256] = st1; sBv[t + 512] = st2;
    // issue phase-1 loads
    st0 = W2v[768 + t]; st1 = W2v[768 + t + 256]; st2 = W2v[768 + t + 512];
    __syncthreads();                     // sH + sB(phase 0) ready

    // ---------------- phase D: 6 staged phases x 6 n-tiles ----------------
    const int arow = w * 16 + cl;
    const unsigned short* ap = sH + arow * 64;
    bf16x8 A0 = *(const bf16x8*)(ap + ((kgrp * 8) ^ bx));
    bf16x8 A1 = *(const bf16x8*)(ap + ((32 + kgrp * 8) ^ bx));

    float r1a[4] = {0,0,0,0}, r4a[4] = {0,0,0,0}, Tt[4] = {0,0,0,0};
    float P0[4] = {0,0,0,0}, P1[4] = {0,0,0,0}, P2[4] = {0,0,0,0};
    const int e0 = w * 16 + kgrp * 4;

#pragma unroll
    for (int p = 0; p < 6; ++p) {
        if (p > 0) {
            __syncthreads();             // everyone done reading phase p-1
            sBv[t] = st0; sBv[t + 256] = st1; sBv[t + 512] = st2;
            if (p < 5) {                 // issue phase p+1 loads (fly under compute)
                st0 = W2v[(p + 1) * 768 + t];
                st1 = W2v[(p + 1) * 768 + t + 256];
                st2 = W2v[(p + 1) * 768 + t + 512];
            }
            __syncthreads();             // sB(phase p) ready
        }
#pragma unroll
        for (int nt = 0; nt < 6; ++nt) {
            const int gnt = p * 6 + nt;  // global n-tile 0..35 (compile-time)
            const unsigned short* bp = sB + (nt * 16 + cl) * 64;
            bf16x8 B0 = *(const bf16x8*)(bp + ((kgrp * 8) ^ bx));
            bf16x8 B1 = *(const bf16x8*)(bp + ((32 + kgrp * 8) ^ bx));
            f32x4 c = {0.f, 0.f, 0.f, 0.f};
            c = __builtin_amdgcn_mfma_f32_16x16x32_bf16(A0, B0, c, 0, 0, 0);
            c = __builtin_amdgcn_mfma_f32_16x16x32_bf16(A1, B1, c, 0, 0, 0);
            if (gnt < 16) {                       // region 1: u = gnt, wo = cl
#pragma unroll
                for (int r = 0; r < 4; ++r) r1a[r] += xq_s[(e0 + r) * XQS + gnt] * c[r];
            } else if (gnt < 24) {                // region 2
                const int u = (gnt - 16) * 2 + ((lane >> 3) & 1);
#pragma unroll
                for (int r = 0; r < 4; ++r) Tt[r] += xq_s[(e0 + r) * XQS + u] * c[r];
            } else if (gnt < 28) {                // region 3
                const int u = (gnt - 24) * 2 + ((lane >> 3) & 1);
#pragma unroll
                for (int r = 0; r < 4; ++r) {
                    const float* xp = xq_s + (e0 + r) * XQS + 16 + u * 3;
                    P0[r] += xp[0] * c[r];
                    P1[r] += xp[1] * c[r];
                    P2[r] += xp[2] * c[r];
                }
            } else {                              // region 4: u = gnt-28, wo = cl
                const int u = gnt - 28;
#pragma unroll
                for (int r = 0; r < 4; ++r) r4a[r] += xq_s[(e0 + r) * XQS + 40 + u] * c[r];
            }
        }
    }

    // ---------------- final assembly + block-local reduction --------------
#pragma unroll
    for (int r = 0; r < 4; ++r) {
        const int e = e0 + r;
        const float v = xq_s[e * XQS + 48] * r1a[r] + Q4C * r4a[r];
        atomicAdd(&racc[p0_s[e] * 40 + cl], v);
    }
#pragma unroll
    for (int r = 0; r < 4; ++r) {
        Tt[r] += __shfl_xor(Tt[r], 8);
        P0[r] += __shfl_xor(P0[r], 8);
        P1[r] += __shfl_xor(P1[r], 8);
        P2[r] += __shfl_xor(P2[r], 8);
    }
    if ((lane & 8) == 0) {
        const int wo = lane & 7;
#pragma unroll
        for (int r = 0; r < 4; ++r) {
            const int e = e0 + r;
            const float q3  = xq_s[e * XQS + 49];
            const float y1x = xq_s[e * XQS + 50];
            const float y1y = xq_s[e * XQS + 51];
            const float y1z = xq_s[e * XQS + 52];
            float* rp = &racc[p0_s[e] * 40 + 16 + wo * 3];
            atomicAdd(rp + 0, KP1C * y1x * Tt[r] + q3 * P0[r]);
            atomicAdd(rp + 1, KP1C * y1y * Tt[r] + q3 * P1[r]);
            atomicAdd(rp + 2, KP1C * y1z * Tt[r] + q3 * P2[r]);
        }
    }
    __syncthreads();
    if (t < 64 && p0_s[t] == t) {
        float* op = out + (size_t)src_s[t] * 40;
        const float* rp = racc + t * 40;
#pragma unroll
        for (int cc = 0; cc < 40; ++cc) atomicAdd(op + cc, rp[cc]);
    }
}

// ============================================================================
// Fallback (ws too small): R0's proven per-edge atomic kernel
// ============================================================================
template <int NC>
__device__ __forceinline__ void gemm_cols(const float* __restrict__ base,
                                          const float (&h)[64], float (&w)[NC]) {
#pragma unroll
    for (int i = 0; i < NC; ++i) w[i] = 0.f;
#pragma unroll
    for (int k = 0; k < 64; ++k) {
        const float4* r4 = (const float4*)(base + k * 576);
        const float hk = h[k];
#pragma unroll
        for (int q = 0; q < NC / 4; ++q) {
            float4 a = r4[q];
            w[q * 4 + 0] += hk * a.x;  w[q * 4 + 1] += hk * a.y;
            w[q * 4 + 2] += hk * a.z;  w[q * 4 + 3] += hk * a.w;
        }
    }
}

__global__ __launch_bounds__(256) void conv_atomic(
    const float* __restrict__ node_input,
    const int* __restrict__ edge_src,
    const int* __restrict__ edge_dst,
    const float* __restrict__ edge_attr,
    const float* __restrict__ dist_embedding,
    const float* __restrict__ W1,
    const float* __restrict__ W2,
    float* __restrict__ out)
{
    __shared__ float sX[256 * 44];
    const int e = blockIdx.x * 256 + threadIdx.x;
    if (e >= N_EDGES) return;
    float* xs = &sX[threadIdx.x * 44];

    float z[64];
#pragma unroll
    for (int k = 0; k < 64; ++k) z[k] = 0.f;
    const float4* dp = (const float4*)(dist_embedding + (size_t)e * 64);
#pragma unroll 2
    for (int j4 = 0; j4 < 16; ++j4) {
        float4 d4 = dp[j4];
        float dj[4] = {d4.x, d4.y, d4.z, d4.w};
#pragma unroll
        for (int r = 0; r < 4; ++r) {
            const float4* w1r = (const float4*)(W1 + (j4 * 4 + r) * 64);
            const float dv = dj[r];
#pragma unroll
            for (int k4 = 0; k4 < 16; ++k4) {
                float4 a = w1r[k4];
                z[k4 * 4 + 0] += dv * a.x; z[k4 * 4 + 1] += dv * a.y;
                z[k4 * 4 + 2] += dv * a.z; z[k4 * 4 + 3] += dv * a.w;
            }
        }
    }
    float h[64];
#pragma unroll
    for (int k = 0; k < 64; ++k) {
        const float zz = 0.125f * z[k];
        h[k] = SILU_NORM * __fdividef(zz, 1.f + __expf(-zz));
    }
    const int dst = edge_dst[e];
    const float4* xr = (const float4*)(node_input + (size_t)dst * 40);
    float4* xd = (float4*)xs;
#pragma unroll
    for (int i = 0; i < 10; ++i) xd[i] = xr[i];
    const float4 yv = *(const float4*)(edge_attr + (size_t)e * 4);
    const float q0 = PW0 * yv.x * SCC;
    const float q4 = PW0 * INV_SQRT3 * SCC;
    const float q20 = KP1C * yv.y, q21 = KP1C * yv.z, q22 = KP1C * yv.w;
    const float q3 = KP1C * yv.x;
    float o0[16], o1[24];
#pragma unroll
    for (int i = 0; i < 16; ++i) o0[i] = 0.f;
#pragma unroll
    for (int i = 0; i < 24; ++i) o1[i] = 0.f;
#pragma unroll 1
    for (int u = 0; u < 16; ++u) {
        float w[16];
        gemm_cols<16>(W2 + u * 16, h, w);
        const float coef = q0 * xs[u];
#pragma unroll
        for (int i = 0; i < 16; ++i) o0[i] += coef * w[i];
    }
#pragma unroll 1
    for (int u = 0; u < 16; ++u) {
        float w[8];
        gemm_cols<8>(W2 + 256 + u * 8, h, w);
        const float xv = xs[u];
        const float c0 = q20 * xv, c1 = q21 * xv, c2 = q22 * xv;
#pragma unroll
        for (int i = 0; i < 8; ++i) {
            o1[i * 3 + 0] += c0 * w[i]; o1[i * 3 + 1] += c1 * w[i]; o1[i * 3 + 2] += c2 * w[i];
        }
    }
#pragma unroll 1
    for (int u = 0; u < 8; ++u) {
        float w[8];
        gemm_cols<8>(W2 + 384 + u * 8, h, w);
        const float c0 = q3 * xs[16 + u * 3 + 0];
        const float c1 = q3 * xs[16 + u * 3 + 1];
        const float c2 = q3 * xs[16 + u * 3 + 2];
#pragma unroll
        for (int i = 0; i < 8; ++i) {
            o1[i * 3 + 0] += c0 * w[i]; o1[i * 3 + 1] += c1 * w[i]; o1[i * 3 + 2] += c2 * w[i];
        }
    }
#pragma unroll 1
    for (int u = 0; u < 8; ++u) {
        float w[16];
        gemm_cols<16>(W2 + 448 + u * 16, h, w);
        const float b = q4 * (xs[16 + u * 3 + 0] * yv.y +
                              xs[16 + u * 3 + 1] * yv.z +
                              xs[16 + u * 3 + 2] * yv.w);
#pragma unroll
        for (int i = 0; i < 16; ++i) o0[i] += b * w[i];
    }
    const int src = edge_src[e];
    float* op = out + (size_t)src * 40;
#pragma unroll
    for (int i = 0; i < 16; ++i) atomicAdd(op + i, o0[i]);
#pragma unroll
    for (int i = 0; i < 24; ++i) atomicAdd(op + 16 + i, o1[i]);
}

// ============================================================================
extern "C" void kernel_launch(void* const* d_in, const int* in_sizes, int n_in,
                              void* d_out, int out_size, void* d_ws, size_t ws_size,
                              hipStream_t stream)
{
    const float* node_input     = (const float*)d_in[0];
    const int*   edge_src       = (const int*)d_in[1];
    const int*   edge_dst       = (const int*)d_in[2];
    const float* edge_attr      = (const float*)d_in[3];
    const float* dist_embedding = (const float*)d_in[4];
    const float* W1             = (const float*)d_in[5];
    const float* W2             = (const float*)d_in[6];
    float* out = (float*)d_out;

    hipMemsetAsync(out, 0, (size_t)out_size * sizeof(float), stream);

    if (ws_size < WS_REQ_BYTES || d_ws == nullptr) {
        dim3 grid((N_EDGES + 255) / 256);
        conv_atomic<<<grid, 256, 0, stream>>>(node_input, edge_src, edge_dst,
                                              edge_attr, dist_embedding, W1, W2, out);
        return;
    }

    int* wsI = (int*)d_ws;
    int* cnt  = wsI + WS_CNT;
    int* cur  = wsI + WS_CUR;
    int* eidx = wsI + WS_EIDX;
    unsigned short* W1Tg = (unsigned short*)(wsI + WS_W1T);
    unsigned short* W2Tg = (unsigned short*)(wsI + WS_W2T);

    hipMemsetAsync(cnt, 0, (size_t)N_NODES * sizeof(int), stream);
    k_preph<<<dim3((N_EDGES + 255) / 256), 256, 0, stream>>>(edge_src, cnt,
                                                             W1, W2, W1Tg, W2Tg);
    k_scan<<<dim3(1), 1024, 0, stream>>>(cnt, cur);
    k_scatter<<<dim3((N_EDGES + 255) / 256), 256, 0, stream>>>(edge_src, cur, eidx);
    k_conv<<<dim3(N_EDGES / 64), 256, 0, stream>>>(node_input, edge_src, edge_dst,
                                                   edge_attr, dist_embedding,
                                                   W1Tg, W2Tg, eidx, out);
}